// Round 14
// baseline (314.222 us; speedup 1.0000x reference)
//
#include <hip/hip_runtime.h>
#include <hip/hip_bf16.h>

// EGNN layer (MC_E_GCL). Round 14: TE=32 edge tiles -> ~30.2 KB LDS ->
// 4 blocks/CU (32 waves/CU, 2x round-12's latency hiding; fits even a 128KB
// usable-LDS pool, which round 13 exposed: 45.5KB*3 > 128KB never placed).
// Staging: 16 threads/edge; rad: 1 pair/thread. Else identical to round 12.

typedef __attribute__((ext_vector_type(8))) short short8;
typedef __attribute__((ext_vector_type(4))) short short4v;
typedef __attribute__((ext_vector_type(4))) float f32x4;

constexpr int TE = 32;    // edges per tile

__device__ __forceinline__ float silu_f(float x) {
    return x / (1.0f + __expf(-x));
}
__device__ __forceinline__ float bf2f(__hip_bfloat16 b) { return __bfloat162float(b); }

// ---------------------------------------------------------------------------
// Setup A (fused): weight transposes + bf16 h table + {deg histogram, norms}.
// ---------------------------------------------------------------------------
constexpr int PREP_ITEMS = 120960;
constexpr int PREP_B     = (PREP_ITEMS + 255) / 256;   // 473
constexpr int HIST_B     = 640;

__global__ void k_prep_all(const float* __restrict__ e_w1, const float* __restrict__ e_w2,
                           const float* __restrict__ c_w1, const float* __restrict__ c_wout,
                           const float* __restrict__ n_w1, const float* __restrict__ n_w2,
                           const float* __restrict__ h,
                           const float* __restrict__ coord,
                           const int* __restrict__ row, const int* __restrict__ col,
                           __hip_bfloat16* __restrict__ w1t, __hip_bfloat16* __restrict__ w2t,
                           __hip_bfloat16* __restrict__ c1t, __hip_bfloat16* __restrict__ cwt,
                           __hip_bfloat16* __restrict__ nw1t, __hip_bfloat16* __restrict__ nw2t,
                           __hip_bfloat16* __restrict__ hb, int hTotal,
                           int* __restrict__ deg, float* __restrict__ norm_acc, int E,
                           int prepH_B)
{
    __shared__ float s_red[32];

    if (blockIdx.x < PREP_B) {
        const int i = blockIdx.x * 256 + threadIdx.x;
        if (i < 36864) {                       // e_w1^T [128][288]
            const int n = i / 288, k = i - n * 288;
            w1t[i] = __float2bfloat16(e_w1[k * 128 + n]);
        } else if (i < 53248) {                // e_w2^T [128][128]
            const int j = i - 36864, n = j >> 7, k = j & 127;
            w2t[j] = __float2bfloat16(e_w2[k * 128 + n]);
        } else if (i < 69632) {                // c_w1^T [128][128]
            const int j = i - 53248, n = j >> 7, k = j & 127;
            c1t[j] = __float2bfloat16(c_w1[k * 128 + n]);
        } else if (i < 71808) {                // c_wout^T padded [16][136]
            const int j = i - 69632, n = j / 136, k = j - n * 136;
            cwt[j] = (n < 4 && k < 128) ? __float2bfloat16(c_wout[k * 4 + n])
                                        : __float2bfloat16(0.0f);
        } else if (i < 104576) {               // n_w1^T [128][256]
            const int j = i - 71808, n = j >> 8, k = j & 255;
            nw1t[j] = __float2bfloat16(n_w1[k * 128 + n]);
        } else if (i < 120960) {               // n_w2^T [128][128]
            const int j = i - 104576, n = j >> 7, k = j & 127;
            nw2t[j] = __float2bfloat16(n_w2[k * 128 + n]);
        }
        return;
    }
    if (blockIdx.x < PREP_B + prepH_B) {       // h -> bf16 table
        const int i = (blockIdx.x - PREP_B) * 256 + threadIdx.x;
        if (i * 2 < hTotal) {
            const float2 v = *(const float2*)&h[i * 2];
            union { ushort2 u; __hip_bfloat16 b[2]; } p;
            p.b[0] = __float2bfloat16(v.x);
            p.b[1] = __float2bfloat16(v.y);
            *(ushort2*)&hb[i * 2] = p.u;
        }
        return;
    }

    // ---- histogram + norm accumulators (grid-stride over edges) ----
    const int hb0 = PREP_B + prepH_B;
    float p[32];
#pragma unroll
    for (int i = 0; i < 32; ++i) p[i] = 0.0f;

    for (int e = (blockIdx.x - hb0) * blockDim.x + threadIdx.x; e < E;
         e += HIST_B * blockDim.x) {
        const int r = row[e], c = col[e];
        atomicAdd(&deg[r], 1);
        float ci[12], cj[12], d[12];
#pragma unroll
        for (int i = 0; i < 12; ++i) {
            ci[i] = coord[r * 12 + i];
            cj[i] = coord[c * 12 + i];
            d[i] = ci[i] - cj[i];
        }
#pragma unroll
        for (int a = 0; a < 4; ++a) {
#pragma unroll
            for (int b = 0; b < 4; ++b) {
                const float rad = d[a*3+0]*d[b*3+0] + d[a*3+1]*d[b*3+1] + d[a*3+2]*d[b*3+2];
                p[a*8 + b] += rad * rad;
                const float dx = ci[a*3+0] - cj[b*3+0];
                const float dy = ci[a*3+1] - cj[b*3+1];
                const float dz = ci[a*3+2] - cj[b*3+2];
                p[a*8 + 4 + b] += dx*dx + dy*dy + dz*dz;   // dist^2 (no sqrt)
            }
        }
    }

    if (threadIdx.x < 32) s_red[threadIdx.x] = 0.0f;
    __syncthreads();
#pragma unroll
    for (int i = 0; i < 32; ++i) {
        float v = p[i];
        for (int off = 32; off >= 1; off >>= 1) v += __shfl_down(v, off, 64);
        if ((threadIdx.x & 63) == 0) atomicAdd(&s_red[i], v);
    }
    __syncthreads();
    if (threadIdx.x < 32) atomicAdd(&norm_acc[threadIdx.x], s_red[threadIdx.x]);
}

// ---------------------------------------------------------------------------
// Setup C: 1024-thread scan of deg -> row_ptr ; + inv-norm finalize.
// ---------------------------------------------------------------------------
__global__ void k_scanfin(const int* __restrict__ deg, int* __restrict__ row_ptr,
                          const float* __restrict__ norm_acc, float* __restrict__ inv_norm,
                          int N)
{
    const int t = threadIdx.x;
    if (t < 32) inv_norm[t] = 1.0f / fmaxf(sqrtf(norm_acc[t]), 1e-12f);

    __shared__ int s[1024];
    const int chunk = (N + 1023) / 1024;
    const int lo = t * chunk, hi = min(lo + chunk, N);
    int sum = 0;
    for (int i = lo; i < hi; ++i) sum += deg[i];
    s[t] = sum;
    __syncthreads();
    for (int off = 1; off < 1024; off <<= 1) {
        int v = (t >= off) ? s[t - off] : 0;
        __syncthreads();
        s[t] += v;
        __syncthreads();
    }
    int running = s[t] - sum;
    for (int i = lo; i < hi; ++i) { row_ptr[i] = running; running += deg[i]; }
    if (hi == N) row_ptr[N] = running + (s[1023] - s[t]);
}

__global__ void k_scatter(const int* __restrict__ row, const int* __restrict__ row_ptr,
                          int* __restrict__ cur, int* __restrict__ csr, int E)
{
    const int e = blockIdx.x * 256 + threadIdx.x;
    if (e < E) {
        const int r = row[e];
        const int idx = row_ptr[r] + atomicAdd(&cur[r], 1);
        csr[idx] = e;
    }
}

// ---------------------------------------------------------------------------
// Edge pipeline: 32-edge sorted tiles, 8 waves x 16 neurons (2 ef each).
// ~30.2 KB LDS -> 4 blocks/CU.
// ---------------------------------------------------------------------------
constexpr int XS = 296;   // 256 h_row|h_col + 32 rad + 8 pad
constexpr int BS = 136;   // 128 + 8 pad

__global__ __launch_bounds__(512, 4) void k_edge_mfma(
    const __hip_bfloat16* __restrict__ hb, const float* __restrict__ coord,
    const int* __restrict__ row, const int* __restrict__ col,
    const int* __restrict__ csr,
    const __hip_bfloat16* __restrict__ w1t, const __hip_bfloat16* __restrict__ w2t,
    const __hip_bfloat16* __restrict__ c1t, const __hip_bfloat16* __restrict__ cwt,
    const float* __restrict__ e_b1, const float* __restrict__ e_b2,
    const float* __restrict__ c_b1, const float* __restrict__ inv_norm,
    float* __restrict__ nagg, float* __restrict__ cagg,
    int E, int nTiles)
{
    __shared__ __hip_bfloat16 sX[TE][XS];
    __shared__ __hip_bfloat16 sB1[TE][BS];
    __shared__ float s_diff[TE][12];
    __shared__ float s_w[TE][4];
    __shared__ float s_inv[32];
    __shared__ int   s_rowv[TE];
    __shared__ int   s_segid[TE];
    __shared__ int   s_segstart[TE + 1];
    __shared__ int   s_segrow[TE];
    __shared__ int   s_nseg;
    __hip_bfloat16 (*sB2)[BS] = (__hip_bfloat16 (*)[BS])&sX[0][0];   // alias sX
    float (*s_ci)[12] = (float (*)[12])&sB1[0][0];                    // alias sB1
    float (*s_cj)[12] = s_ci + TE;

    const int tid = threadIdx.x;
    const int wv = tid >> 6;
    const int lane = tid & 63, l15 = lane & 15;
    const int kq = (lane >> 4) * 8;
    const int jr = (lane >> 4) * 4;
    const int nb = wv * 16 + jr;

    if (tid < 32) s_inv[tid] = inv_norm[tid];

    // register/AGPR-resident weights + biases + c_wout fragments
    short8 w1f[9], w2f[4], w3f[4], cwtf[4];
    float b1v[4], b2v[4], b3v[4];
    {
        const int nrow = wv * 16 + l15;
#pragma unroll
        for (int s = 0; s < 9; ++s) w1f[s] = *(const short8*)&w1t[nrow * 288 + s * 32 + kq];
#pragma unroll
        for (int s = 0; s < 4; ++s) w2f[s] = *(const short8*)&w2t[nrow * 128 + s * 32 + kq];
#pragma unroll
        for (int s = 0; s < 4; ++s) w3f[s] = *(const short8*)&c1t[nrow * 128 + s * 32 + kq];
#pragma unroll
        for (int s = 0; s < 4; ++s) cwtf[s] = *(const short8*)&cwt[l15 * 136 + s * 32 + kq];
#pragma unroll
        for (int j = 0; j < 4; ++j) {
            b1v[j] = e_b1[nb + j]; b2v[j] = e_b2[nb + j]; b3v[j] = c_b1[nb + j];
        }
    }
    __syncthreads();

    for (int tile = blockIdx.x; tile < nTiles; tile += gridDim.x) {
        const int e0 = tile * TE;
        const int nE = min(TE, E - e0);

        // ---- phase A: stage h[row], h[col]; 16 threads/edge ----
        {
            const int e = tid >> 4, p = tid & 15;
            if (e < nE) {
                const int eid = csr[e0 + e];
                const int r = row[eid], c = col[eid];
                if (p < 8) {
                    const __hip_bfloat16* hr = &hb[(size_t)r * 128 + p * 16];
                    *(short8*)&sX[e][p * 16]     = *(const short8*)(hr);
                    *(short8*)&sX[e][p * 16 + 8] = *(const short8*)(hr + 8);
                    if (p == 0) {
                        s_rowv[e] = r;
                        *(float4*)&s_ci[e][0] = *(const float4*)&coord[r * 12];
                        *(float4*)&s_ci[e][4] = *(const float4*)&coord[r * 12 + 4];
                        *(float4*)&s_ci[e][8] = *(const float4*)&coord[r * 12 + 8];
                    } else if (p == 1) {
                        *(float4*)&s_cj[e][0] = *(const float4*)&coord[c * 12];
                        *(float4*)&s_cj[e][4] = *(const float4*)&coord[c * 12 + 4];
                        *(float4*)&s_cj[e][8] = *(const float4*)&coord[c * 12 + 8];
                    }
                } else {
                    const int q = p - 8;
                    const __hip_bfloat16* hc = &hb[(size_t)c * 128 + q * 16];
                    *(short8*)&sX[e][128 + q * 16]     = *(const short8*)(hc);
                    *(short8*)&sX[e][128 + q * 16 + 8] = *(const short8*)(hc + 8);
                }
            }
        }
        __syncthreads();   // B1

        // ---- phase B: rad features (1 pair/thread) + segment build ----
        {
            const int e = tid >> 4, pr = tid & 15;
            if (e < nE) {
                const int a = pr >> 2, b = pr & 3;
                const float cax = s_ci[e][a*3], cay = s_ci[e][a*3+1], caz = s_ci[e][a*3+2];
                const float jax = s_cj[e][a*3], jay = s_cj[e][a*3+1], jaz = s_cj[e][a*3+2];
                const float cbx = s_ci[e][b*3], cby = s_ci[e][b*3+1], cbz = s_ci[e][b*3+2];
                const float jbx = s_cj[e][b*3], jby = s_cj[e][b*3+1], jbz = s_cj[e][b*3+2];
                const float dax = cax - jax, day = cay - jay, daz = caz - jaz;
                const float dbx = cbx - jbx, dby = cby - jby, dbz = cbz - jbz;
                const float rad = dax*dbx + day*dby + daz*dbz;
                const float dx = cax - jbx, dy = cay - jby, dz = caz - jbz;
                const float ds = sqrtf(dx*dx + dy*dy + dz*dz);
                sX[e][256 + a*8 + b]     = __float2bfloat16(rad * s_inv[a*8 + b]);
                sX[e][256 + a*8 + 4 + b] = __float2bfloat16(ds  * s_inv[a*8 + 4 + b]);
                if (a == b) {
                    s_diff[e][a*3] = dax; s_diff[e][a*3+1] = day; s_diff[e][a*3+2] = daz;
                }
            }
        }
        if (tid < 64) {
            const int i = tid;
            const bool valid = i < nE;
            const int r = valid ? s_rowv[i] : -1;
            const bool flag = valid && (i == 0 || r != s_rowv[i - 1]);
            const unsigned long long mask = __ballot(flag);
            if (flag) {
                const int s = (i == 0) ? 0 : __popcll(mask & ((1ull << i) - 1));
                s_segstart[s] = i;
                s_segrow[s] = r;
            }
            const unsigned long long upto =
                (i == 63) ? ~0ull : ((1ull << (i + 1)) - 1);
            if (valid) s_segid[i] = __popcll(mask & upto) - 1;
            if (i == 0) {
                const int nseg = __popcll(mask);
                s_nseg = nseg;
                s_segstart[nseg] = nE;
            }
        }
        __syncthreads();   // B2

        f32x4 acc[2];

        // ---- layer 1: eh @ W1 -> silu -> sB1 ----
#pragma unroll
        for (int ef = 0; ef < 2; ++ef) {
            acc[ef][0] = b1v[0]; acc[ef][1] = b1v[1]; acc[ef][2] = b1v[2]; acc[ef][3] = b1v[3];
        }
#pragma unroll
        for (int s = 0; s < 9; ++s) {
            const short8 a = w1f[s];
#pragma unroll
            for (int ef = 0; ef < 2; ++ef) {
                const short8 b = *(const short8*)&sX[ef * 16 + l15][s * 32 + kq];
                acc[ef] = __builtin_amdgcn_mfma_f32_16x16x32_bf16(a, b, acc[ef], 0, 0, 0);
            }
        }
#pragma unroll
        for (int ef = 0; ef < 2; ++ef) {
            union { short4v s; __hip_bfloat16 b[4]; } u;
#pragma unroll
            for (int j = 0; j < 4; ++j) u.b[j] = __float2bfloat16(silu_f(acc[ef][j]));
            *(short4v*)&sB1[ef * 16 + l15][nb] = u.s;
        }
        __syncthreads();   // B3

        // ---- layer 2: sB1 @ W2 -> silu = m -> sB2 (sX alias; sX reads done) ----
#pragma unroll
        for (int ef = 0; ef < 2; ++ef) {
            acc[ef][0] = b2v[0]; acc[ef][1] = b2v[1]; acc[ef][2] = b2v[2]; acc[ef][3] = b2v[3];
        }
#pragma unroll
        for (int s = 0; s < 4; ++s) {
            const short8 a = w2f[s];
#pragma unroll
            for (int ef = 0; ef < 2; ++ef) {
                const short8 b = *(const short8*)&sB1[ef * 16 + l15][s * 32 + kq];
                acc[ef] = __builtin_amdgcn_mfma_f32_16x16x32_bf16(a, b, acc[ef], 0, 0, 0);
            }
        }
#pragma unroll
        for (int ef = 0; ef < 2; ++ef) {
            union { short4v s; __hip_bfloat16 b[4]; } u;
#pragma unroll
            for (int j = 0; j < 4; ++j) u.b[j] = __float2bfloat16(silu_f(acc[ef][j]));
            *(short4v*)&sB2[ef * 16 + l15][nb] = u.s;
        }
        __syncthreads();   // B4

        // ---- layer 3: m @ c_w1 -> silu -> sB1 ; parallel nagg run-sum ----
#pragma unroll
        for (int ef = 0; ef < 2; ++ef) {
            acc[ef][0] = b3v[0]; acc[ef][1] = b3v[1]; acc[ef][2] = b3v[2]; acc[ef][3] = b3v[3];
        }
#pragma unroll
        for (int s = 0; s < 4; ++s) {
            const short8 a = w3f[s];
#pragma unroll
            for (int ef = 0; ef < 2; ++ef) {
                const short8 b = *(const short8*)&sB2[ef * 16 + l15][s * 32 + kq];
                acc[ef] = __builtin_amdgcn_mfma_f32_16x16x32_bf16(a, b, acc[ef], 0, 0, 0);
            }
        }
        // nagg: 16-edge run per (half, channel); windows beyond nE skip.
        {
            const int q = tid >> 7, c = tid & 127;
            int e = q * 16;
            const int eend = min(e + 16, nE);
            if (e < eend) {
                int cur = s_segid[e];
                float sum = 0.0f;
                for (; e < eend; ++e) {
                    const int sg = s_segid[e];
                    if (sg != cur) {
                        atomicAdd(&nagg[(size_t)s_segrow[cur] * 128 + c], sum);
                        sum = 0.0f; cur = sg;
                    }
                    sum += bf2f(sB2[e][c]);
                }
                atomicAdd(&nagg[(size_t)s_segrow[cur] * 128 + c], sum);
            }
        }
#pragma unroll
        for (int ef = 0; ef < 2; ++ef) {
            union { short4v s; __hip_bfloat16 b[4]; } u;
#pragma unroll
            for (int j = 0; j < 4; ++j) u.b[j] = __float2bfloat16(silu_f(acc[ef][j]));
            *(short4v*)&sB1[ef * 16 + l15][nb] = u.s;
        }
        __syncthreads();   // B5

        // ---- coord-out via MFMA (register cwtf): s_w = sB1 @ c_wout^T ----
        if (wv < 2) {
            f32x4 cacc = {0.0f, 0.0f, 0.0f, 0.0f};
#pragma unroll
            for (int s = 0; s < 4; ++s) {
                const short8 b = *(const short8*)&sB1[wv * 16 + l15][s * 32 + kq];
                cacc = __builtin_amdgcn_mfma_f32_16x16x32_bf16(cwtf[s], b, cacc, 0, 0, 0);
            }
            if (lane < 16) {
#pragma unroll
                for (int j = 0; j < 4; ++j) s_w[wv * 16 + l15][j] = cacc[j];
            }
        }
        __syncthreads();   // B6

        // ---- cagg: parallel segmented reduction over (seg, half, dd) ----
        {
            const int nseg = s_nseg;
            const int items = nseg * 24;
            for (int i = tid; i < items; i += 512) {
                const int s = i / 24, r = i - s * 24;
                const int q = r / 12, dd = r - q * 12;
                const int b  = max(s_segstart[s], q * 16);
                const int en = min(s_segstart[s + 1], q * 16 + 16);
                if (b < en) {
                    float sum = 0.0f;
                    for (int e = b; e < en; ++e)
                        sum += s_diff[e][dd] * s_w[e][dd / 3];
                    atomicAdd(&cagg[(size_t)s_segrow[s] * 12 + dd], sum);
                }
            }
        }
        __syncthreads();   // B7
    }
}

// ---------------------------------------------------------------------------
// Node MLP on MFMA: 64-node tiles, 8 waves x 16 neurons, register weights.
// ---------------------------------------------------------------------------
constexpr int NXS = 264;  // 256 + 8 pad

__global__ __launch_bounds__(512, 2) void k_node_mfma(
    const float* __restrict__ h, const float* __restrict__ nagg,
    const __hip_bfloat16* __restrict__ nw1t, const __hip_bfloat16* __restrict__ nw2t,
    const float* __restrict__ n_b1, const float* __restrict__ n_b2,
    const float* __restrict__ coord, const float* __restrict__ cagg,
    const int* __restrict__ row_ptr,
    float* __restrict__ out_h, float* __restrict__ out_coord, int N)
{
    __shared__ __hip_bfloat16 sX[64][NXS];
    __shared__ __hip_bfloat16 sB[64][BS];

    const int tid = threadIdx.x;
    const int wv = tid >> 6;
    const int lane = tid & 63, l15 = lane & 15;
    const int kq = (lane >> 4) * 8;
    const int jr = (lane >> 4) * 4;
    const int nb = wv * 16 + jr;

    short8 w1f[8], w2f[4];
    float b1v[4], b2v[4];
    {
        const int nrow = wv * 16 + l15;
#pragma unroll
        for (int s = 0; s < 8; ++s) w1f[s] = *(const short8*)&nw1t[nrow * 256 + s * 32 + kq];
#pragma unroll
        for (int s = 0; s < 4; ++s) w2f[s] = *(const short8*)&nw2t[nrow * 128 + s * 32 + kq];
#pragma unroll
        for (int j = 0; j < 4; ++j) { b1v[j] = n_b1[nb + j]; b2v[j] = n_b2[nb + j]; }
    }

    const int n0 = blockIdx.x * 64;
    const int nN = min(64, N - n0);

    // coord epilogue (independent of the MLP)
    for (int i = tid; i < nN * 12; i += 512) {
        const int e = i / 12, dd = i - e * 12;
        const int n = n0 + e;
        const float cntv = (float)(row_ptr[n + 1] - row_ptr[n]);
        out_coord[n * 12 + dd] = coord[n * 12 + dd] + cagg[n * 12 + dd] / fmaxf(cntv, 1.0f);
    }

    // stage X = [h | nagg] as bf16
    {
        const int e = tid >> 3, p = tid & 7;
        const int n = n0 + e;
        union { short8 s; __hip_bfloat16 b[8]; } u;
        if (e < nN) {
            const float* src = (p < 4) ? &h[(size_t)n * 128 + p * 32]
                                       : &nagg[(size_t)n * 128 + (p - 4) * 32];
#pragma unroll
            for (int i = 0; i < 4; ++i) {
                const float4 v0 = *(const float4*)(src + i * 8);
                const float4 v1 = *(const float4*)(src + i * 8 + 4);
                u.b[0] = __float2bfloat16(v0.x); u.b[1] = __float2bfloat16(v0.y);
                u.b[2] = __float2bfloat16(v0.z); u.b[3] = __float2bfloat16(v0.w);
                u.b[4] = __float2bfloat16(v1.x); u.b[5] = __float2bfloat16(v1.y);
                u.b[6] = __float2bfloat16(v1.z); u.b[7] = __float2bfloat16(v1.w);
                *(short8*)&sX[e][p * 32 + i * 8] = u.s;
            }
        } else {
#pragma unroll
            for (int j = 0; j < 8; ++j) u.b[j] = __float2bfloat16(0.0f);
#pragma unroll
            for (int i = 0; i < 4; ++i) *(short8*)&sX[e][p * 32 + i * 8] = u.s;
        }
    }
    __syncthreads();

    f32x4 acc[4];
#pragma unroll
    for (int ef = 0; ef < 4; ++ef) {
        acc[ef][0] = b1v[0]; acc[ef][1] = b1v[1]; acc[ef][2] = b1v[2]; acc[ef][3] = b1v[3];
    }
#pragma unroll
    for (int s = 0; s < 8; ++s) {
        const short8 a = w1f[s];
#pragma unroll
        for (int ef = 0; ef < 4; ++ef) {
            const short8 b = *(const short8*)&sX[ef * 16 + l15][s * 32 + kq];
            acc[ef] = __builtin_amdgcn_mfma_f32_16x16x32_bf16(a, b, acc[ef], 0, 0, 0);
        }
    }
#pragma unroll
    for (int ef = 0; ef < 4; ++ef) {
        union { short4v s; __hip_bfloat16 b[4]; } u;
#pragma unroll
        for (int j = 0; j < 4; ++j) u.b[j] = __float2bfloat16(silu_f(acc[ef][j]));
        *(short4v*)&sB[ef * 16 + l15][nb] = u.s;
    }
    __syncthreads();

#pragma unroll
    for (int ef = 0; ef < 4; ++ef) {
        acc[ef][0] = b2v[0]; acc[ef][1] = b2v[1]; acc[ef][2] = b2v[2]; acc[ef][3] = b2v[3];
    }
#pragma unroll
    for (int s = 0; s < 4; ++s) {
        const short8 a = w2f[s];
#pragma unroll
        for (int ef = 0; ef < 4; ++ef) {
            const short8 b = *(const short8*)&sB[ef * 16 + l15][s * 32 + kq];
            acc[ef] = __builtin_amdgcn_mfma_f32_16x16x32_bf16(a, b, acc[ef], 0, 0, 0);
        }
    }
#pragma unroll
    for (int ef = 0; ef < 4; ++ef) {
        const int e = ef * 16 + l15;
        if (e < nN) {
            const size_t o = (size_t)(n0 + e) * 128 + nb;
            const float4 hv = *(const float4*)&h[o];
            float4 r;
            r.x = hv.x + acc[ef][0]; r.y = hv.y + acc[ef][1];
            r.z = hv.z + acc[ef][2]; r.w = hv.w + acc[ef][3];
            *(float4*)&out_h[o] = r;
        }
    }
}

// ---------------------------------------------------------------------------
extern "C" void kernel_launch(void* const* d_in, const int* in_sizes, int n_in,
                              void* d_out, int out_size, void* d_ws, size_t ws_size,
                              hipStream_t stream)
{
    const float* h      = (const float*)d_in[0];
    const float* coord  = (const float*)d_in[1];
    const int*   row    = (const int*)d_in[2];
    const int*   col    = (const int*)d_in[3];
    const float* e_w1   = (const float*)d_in[4];
    const float* e_b1   = (const float*)d_in[5];
    const float* e_w2   = (const float*)d_in[6];
    const float* e_b2   = (const float*)d_in[7];
    const float* c_w1   = (const float*)d_in[8];
    const float* c_b1   = (const float*)d_in[9];
    const float* c_wout = (const float*)d_in[10];
    const float* n_w1   = (const float*)d_in[11];
    const float* n_b1   = (const float*)d_in[12];
    const float* n_w2   = (const float*)d_in[13];
    const float* n_b2   = (const float*)d_in[14];

    const int E = in_sizes[2];
    const int N = in_sizes[0] / 128;

    // workspace layout (zeroed region first) — ~7.25 MB
    float* ws       = (float*)d_ws;
    float* norm_acc = ws;                               // 32
    int*   deg      = (int*)(ws + 32);                  // N
    int*   cur      = deg + N;                          // N
    float* nagg     = (float*)(cur + N);                // N*128
    float* cagg     = nagg + (size_t)N * 128;           // N*12
    // non-zeroed:
    int*   row_ptr  = (int*)(cagg + (size_t)N * 12);    // N+1 (rounded)
    int*   csr      = row_ptr + ((N + 4) & ~3);         // E
    float* inv_norm = (float*)(csr + E);                // 32
    __hip_bfloat16* w1t  = (__hip_bfloat16*)(inv_norm + 32);  // 36864
    __hip_bfloat16* w2t  = w1t + 36864;                       // 16384
    __hip_bfloat16* c1t  = w2t + 16384;                       // 16384
    __hip_bfloat16* cwt  = c1t + 16384;                       // 2176
    __hip_bfloat16* nw1t = cwt + 2176;                        // 32768
    __hip_bfloat16* nw2t = nw1t + 32768;                      // 16384

    // bf16 h table in d_out (dead until k_node_mfma overwrites it)
    __hip_bfloat16* hb = (__hip_bfloat16*)d_out;              // N*128 bf16

    const size_t zero_bytes = (size_t)(32 + 2 * N + N * 128 + N * 12) * sizeof(float);
    hipMemsetAsync(d_ws, 0, zero_bytes, stream);

    const int prepH_B = (N * 64 + 255) / 256;
    k_prep_all<<<PREP_B + prepH_B + HIST_B, 256, 0, stream>>>(
        e_w1, e_w2, c_w1, c_wout, n_w1, n_w2, h, coord, row, col,
        w1t, w2t, c1t, cwt, nw1t, nw2t, hb, N * 128,
        deg, norm_acc, E, prepH_B);
    k_scanfin<<<1, 1024, 0, stream>>>(deg, row_ptr, norm_acc, inv_norm, N);
    k_scatter<<<(E + 255) / 256, 256, 0, stream>>>(row, row_ptr, cur, csr, E);

    const int nTiles = (E + TE - 1) / TE;
    k_edge_mfma<<<1024, 512, 0, stream>>>(
        hb, coord, row, col, csr, w1t, w2t, c1t, cwt,
        e_b1, e_b2, c_b1, inv_norm, nagg, cagg, E, nTiles);

    float* out_h     = (float*)d_out;
    float* out_coord = out_h + (size_t)N * 128;
    k_node_mfma<<<(N + 63) / 64, 512, 0, stream>>>(
        h, nagg, nw1t, nw2t, n_b1, n_b2, coord, cagg, row_ptr, out_h, out_coord, N);
}

// Round 15
// 285.916 us; speedup vs baseline: 1.0990x; 1.0990x over previous
//
#include <hip/hip_runtime.h>
#include <hip/hip_bf16.h>

// EGNN layer (MC_E_GCL). Round 15: round-12 base (TE=64, champion 248us) with
// a shortened per-tile chain: (1) phases A+B merged (rad computed straight
// from L2-hot global coords; no s_ci/s_cj LDS round trip) -> 6 barriers;
// (2) segment build via direct row loads + shfl (no s_rowv dependency);
// (3) all global atomics batched into the final phase (one vmcnt drain).
// Lesson bank: occupancy is NOT the lever (TE=48/32 both regressed);
// allocator pins 64 arch-VGPR; no register prefetch possible.

typedef __attribute__((ext_vector_type(8))) short short8;
typedef __attribute__((ext_vector_type(4))) short short4v;
typedef __attribute__((ext_vector_type(4))) float f32x4;

constexpr int TE = 64;

__device__ __forceinline__ float silu_f(float x) {
    return x / (1.0f + __expf(-x));
}
__device__ __forceinline__ float bf2f(__hip_bfloat16 b) { return __bfloat162float(b); }

// ---------------------------------------------------------------------------
// Setup A (fused): weight transposes + bf16 h table + {deg histogram, norms}.
// ---------------------------------------------------------------------------
constexpr int PREP_ITEMS = 120960;
constexpr int PREP_B     = (PREP_ITEMS + 255) / 256;   // 473
constexpr int HIST_B     = 640;

__global__ void k_prep_all(const float* __restrict__ e_w1, const float* __restrict__ e_w2,
                           const float* __restrict__ c_w1, const float* __restrict__ c_wout,
                           const float* __restrict__ n_w1, const float* __restrict__ n_w2,
                           const float* __restrict__ h,
                           const float* __restrict__ coord,
                           const int* __restrict__ row, const int* __restrict__ col,
                           __hip_bfloat16* __restrict__ w1t, __hip_bfloat16* __restrict__ w2t,
                           __hip_bfloat16* __restrict__ c1t, __hip_bfloat16* __restrict__ cwt,
                           __hip_bfloat16* __restrict__ nw1t, __hip_bfloat16* __restrict__ nw2t,
                           __hip_bfloat16* __restrict__ hb, int hTotal,
                           int* __restrict__ deg, float* __restrict__ norm_acc, int E,
                           int prepH_B)
{
    __shared__ float s_red[32];

    if (blockIdx.x < PREP_B) {
        const int i = blockIdx.x * 256 + threadIdx.x;
        if (i < 36864) {                       // e_w1^T [128][288]
            const int n = i / 288, k = i - n * 288;
            w1t[i] = __float2bfloat16(e_w1[k * 128 + n]);
        } else if (i < 53248) {                // e_w2^T [128][128]
            const int j = i - 36864, n = j >> 7, k = j & 127;
            w2t[j] = __float2bfloat16(e_w2[k * 128 + n]);
        } else if (i < 69632) {                // c_w1^T [128][128]
            const int j = i - 53248, n = j >> 7, k = j & 127;
            c1t[j] = __float2bfloat16(c_w1[k * 128 + n]);
        } else if (i < 71808) {                // c_wout^T padded [16][136]
            const int j = i - 69632, n = j / 136, k = j - n * 136;
            cwt[j] = (n < 4 && k < 128) ? __float2bfloat16(c_wout[k * 4 + n])
                                        : __float2bfloat16(0.0f);
        } else if (i < 104576) {               // n_w1^T [128][256]
            const int j = i - 71808, n = j >> 8, k = j & 255;
            nw1t[j] = __float2bfloat16(n_w1[k * 128 + n]);
        } else if (i < 120960) {               // n_w2^T [128][128]
            const int j = i - 104576, n = j >> 7, k = j & 127;
            nw2t[j] = __float2bfloat16(n_w2[k * 128 + n]);
        }
        return;
    }
    if (blockIdx.x < PREP_B + prepH_B) {       // h -> bf16 table
        const int i = (blockIdx.x - PREP_B) * 256 + threadIdx.x;
        if (i * 2 < hTotal) {
            const float2 v = *(const float2*)&h[i * 2];
            union { ushort2 u; __hip_bfloat16 b[2]; } p;
            p.b[0] = __float2bfloat16(v.x);
            p.b[1] = __float2bfloat16(v.y);
            *(ushort2*)&hb[i * 2] = p.u;
        }
        return;
    }

    // ---- histogram + norm accumulators (grid-stride over edges) ----
    const int hb0 = PREP_B + prepH_B;
    float p[32];
#pragma unroll
    for (int i = 0; i < 32; ++i) p[i] = 0.0f;

    for (int e = (blockIdx.x - hb0) * blockDim.x + threadIdx.x; e < E;
         e += HIST_B * blockDim.x) {
        const int r = row[e], c = col[e];
        atomicAdd(&deg[r], 1);
        float ci[12], cj[12], d[12];
#pragma unroll
        for (int i = 0; i < 12; ++i) {
            ci[i] = coord[r * 12 + i];
            cj[i] = coord[c * 12 + i];
            d[i] = ci[i] - cj[i];
        }
#pragma unroll
        for (int a = 0; a < 4; ++a) {
#pragma unroll
            for (int b = 0; b < 4; ++b) {
                const float rad = d[a*3+0]*d[b*3+0] + d[a*3+1]*d[b*3+1] + d[a*3+2]*d[b*3+2];
                p[a*8 + b] += rad * rad;
                const float dx = ci[a*3+0] - cj[b*3+0];
                const float dy = ci[a*3+1] - cj[b*3+1];
                const float dz = ci[a*3+2] - cj[b*3+2];
                p[a*8 + 4 + b] += dx*dx + dy*dy + dz*dz;   // dist^2 (no sqrt)
            }
        }
    }

    if (threadIdx.x < 32) s_red[threadIdx.x] = 0.0f;
    __syncthreads();
#pragma unroll
    for (int i = 0; i < 32; ++i) {
        float v = p[i];
        for (int off = 32; off >= 1; off >>= 1) v += __shfl_down(v, off, 64);
        if ((threadIdx.x & 63) == 0) atomicAdd(&s_red[i], v);
    }
    __syncthreads();
    if (threadIdx.x < 32) atomicAdd(&norm_acc[threadIdx.x], s_red[threadIdx.x]);
}

// ---------------------------------------------------------------------------
// Setup C: 1024-thread scan of deg -> row_ptr ; + inv-norm finalize.
// ---------------------------------------------------------------------------
__global__ void k_scanfin(const int* __restrict__ deg, int* __restrict__ row_ptr,
                          const float* __restrict__ norm_acc, float* __restrict__ inv_norm,
                          int N)
{
    const int t = threadIdx.x;
    if (t < 32) inv_norm[t] = 1.0f / fmaxf(sqrtf(norm_acc[t]), 1e-12f);

    __shared__ int s[1024];
    const int chunk = (N + 1023) / 1024;
    const int lo = t * chunk, hi = min(lo + chunk, N);
    int sum = 0;
    for (int i = lo; i < hi; ++i) sum += deg[i];
    s[t] = sum;
    __syncthreads();
    for (int off = 1; off < 1024; off <<= 1) {
        int v = (t >= off) ? s[t - off] : 0;
        __syncthreads();
        s[t] += v;
        __syncthreads();
    }
    int running = s[t] - sum;
    for (int i = lo; i < hi; ++i) { row_ptr[i] = running; running += deg[i]; }
    if (hi == N) row_ptr[N] = running + (s[1023] - s[t]);
}

__global__ void k_scatter(const int* __restrict__ row, const int* __restrict__ row_ptr,
                          int* __restrict__ cur, int* __restrict__ csr, int E)
{
    const int e = blockIdx.x * 256 + threadIdx.x;
    if (e < E) {
        const int r = row[e];
        const int idx = row_ptr[r] + atomicAdd(&cur[r], 1);
        csr[idx] = e;
    }
}

// ---------------------------------------------------------------------------
// Edge pipeline: 64-edge sorted tiles, 8 waves x 16 neurons, 6 barriers/tile.
// ---------------------------------------------------------------------------
constexpr int XS = 296;   // 256 h_row|h_col + 32 rad + 8 pad
constexpr int BS = 136;   // 128 + 8 pad

__global__ __launch_bounds__(512, 4) void k_edge_mfma(
    const __hip_bfloat16* __restrict__ hb, const float* __restrict__ coord,
    const int* __restrict__ row, const int* __restrict__ col,
    const int* __restrict__ csr,
    const __hip_bfloat16* __restrict__ w1t, const __hip_bfloat16* __restrict__ w2t,
    const __hip_bfloat16* __restrict__ c1t, const __hip_bfloat16* __restrict__ cwt,
    const float* __restrict__ e_b1, const float* __restrict__ e_b2,
    const float* __restrict__ c_b1, const float* __restrict__ inv_norm,
    float* __restrict__ nagg, float* __restrict__ cagg,
    int E, int nTiles)
{
    __shared__ __hip_bfloat16 sX[TE][XS];
    __shared__ __hip_bfloat16 sB1[TE][BS];
    __shared__ float s_diff[TE][12];
    __shared__ float s_w[TE][4];
    __shared__ float s_inv[32];
    __shared__ int   s_segid[TE];
    __shared__ int   s_segstart[TE + 1];
    __shared__ int   s_segrow[TE];
    __shared__ int   s_nseg;
    __hip_bfloat16 (*sB2)[BS] = (__hip_bfloat16 (*)[BS])&sX[0][0];   // alias sX

    const int tid = threadIdx.x;
    const int wv = tid >> 6;
    const int lane = tid & 63, l15 = lane & 15;
    const int kq = (lane >> 4) * 8;
    const int jr = (lane >> 4) * 4;
    const int nb = wv * 16 + jr;

    if (tid < 32) s_inv[tid] = inv_norm[tid];

    // register/AGPR-resident weights + biases + c_wout fragments
    short8 w1f[9], w2f[4], w3f[4], cwtf[4];
    float b1v[4], b2v[4], b3v[4];
    {
        const int nrow = wv * 16 + l15;
#pragma unroll
        for (int s = 0; s < 9; ++s) w1f[s] = *(const short8*)&w1t[nrow * 288 + s * 32 + kq];
#pragma unroll
        for (int s = 0; s < 4; ++s) w2f[s] = *(const short8*)&w2t[nrow * 128 + s * 32 + kq];
#pragma unroll
        for (int s = 0; s < 4; ++s) w3f[s] = *(const short8*)&c1t[nrow * 128 + s * 32 + kq];
#pragma unroll
        for (int s = 0; s < 4; ++s) cwtf[s] = *(const short8*)&cwt[l15 * 136 + s * 32 + kq];
#pragma unroll
        for (int j = 0; j < 4; ++j) {
            b1v[j] = e_b1[nb + j]; b2v[j] = e_b2[nb + j]; b3v[j] = c_b1[nb + j];
        }
    }
    __syncthreads();

    for (int tile = blockIdx.x; tile < nTiles; tile += gridDim.x) {
        const int e0 = tile * TE;
        const int nE = min(TE, E - e0);

        // ---- phase A': stage h rows + rad features (global coords) ----
        {
            const int e = tid >> 3, p = tid & 7;
            if (e < nE) {
                const int eid = csr[e0 + e];
                const int r = row[eid], c = col[eid];
                const __hip_bfloat16* hr = &hb[(size_t)r * 128 + p * 16];
                const __hip_bfloat16* hc = &hb[(size_t)c * 128 + p * 16];
                *(short8*)&sX[e][p * 16]           = *(const short8*)(hr);
                *(short8*)&sX[e][p * 16 + 8]       = *(const short8*)(hr + 8);
                *(short8*)&sX[e][128 + p * 16]     = *(const short8*)(hc);
                *(short8*)&sX[e][128 + p * 16 + 8] = *(const short8*)(hc + 8);

                float ci[12], cj[12];
                *(float4*)&ci[0] = *(const float4*)&coord[r * 12];
                *(float4*)&ci[4] = *(const float4*)&coord[r * 12 + 4];
                *(float4*)&ci[8] = *(const float4*)&coord[r * 12 + 8];
                *(float4*)&cj[0] = *(const float4*)&coord[c * 12];
                *(float4*)&cj[4] = *(const float4*)&coord[c * 12 + 4];
                *(float4*)&cj[8] = *(const float4*)&coord[c * 12 + 8];
#pragma unroll
                for (int t2 = 0; t2 < 2; ++t2) {
                    const int pr = p * 2 + t2, a = pr >> 2, b = pr & 3;
                    const float dax = ci[a*3]   - cj[a*3];
                    const float day = ci[a*3+1] - cj[a*3+1];
                    const float daz = ci[a*3+2] - cj[a*3+2];
                    const float dbx = ci[b*3]   - cj[b*3];
                    const float dby = ci[b*3+1] - cj[b*3+1];
                    const float dbz = ci[b*3+2] - cj[b*3+2];
                    const float rad = dax*dbx + day*dby + daz*dbz;
                    const float dx = ci[a*3]   - cj[b*3];
                    const float dy = ci[a*3+1] - cj[b*3+1];
                    const float dz = ci[a*3+2] - cj[b*3+2];
                    const float ds = sqrtf(dx*dx + dy*dy + dz*dz);
                    sX[e][256 + a*8 + b]     = __float2bfloat16(rad * s_inv[a*8 + b]);
                    sX[e][256 + a*8 + 4 + b] = __float2bfloat16(ds  * s_inv[a*8 + 4 + b]);
                    if (a == b) {
                        s_diff[e][a*3] = dax; s_diff[e][a*3+1] = day; s_diff[e][a*3+2] = daz;
                    }
                }
            }
        }
        // segment build (wave 0; independent of LDS writes above)
        if (tid < 64) {
            const int i = tid;
            const bool valid = i < nE;
            int r = -1;
            if (valid) r = row[csr[e0 + i]];
            const int rprev = __shfl_up(r, 1, 64);
            const bool flag = valid && (i == 0 || r != rprev);
            const unsigned long long mask = __ballot(flag);
            if (flag) {
                const int s = (i == 0) ? 0 : __popcll(mask & ((1ull << i) - 1));
                s_segstart[s] = i;
                s_segrow[s] = r;
            }
            const unsigned long long upto =
                (i == 63) ? ~0ull : ((1ull << (i + 1)) - 1);
            if (valid) s_segid[i] = __popcll(mask & upto) - 1;
            if (i == 0) {
                const int nseg = __popcll(mask);
                s_nseg = nseg;
                s_segstart[nseg] = nE;
            }
        }
        __syncthreads();   // B1

        f32x4 acc[4];

        // ---- layer 1: eh @ W1 -> silu -> sB1 ----
#pragma unroll
        for (int ef = 0; ef < 4; ++ef) {
            acc[ef][0] = b1v[0]; acc[ef][1] = b1v[1]; acc[ef][2] = b1v[2]; acc[ef][3] = b1v[3];
        }
#pragma unroll
        for (int s = 0; s < 9; ++s) {
            const short8 a = w1f[s];
#pragma unroll
            for (int ef = 0; ef < 4; ++ef) {
                const short8 b = *(const short8*)&sX[ef * 16 + l15][s * 32 + kq];
                acc[ef] = __builtin_amdgcn_mfma_f32_16x16x32_bf16(a, b, acc[ef], 0, 0, 0);
            }
        }
#pragma unroll
        for (int ef = 0; ef < 4; ++ef) {
            union { short4v s; __hip_bfloat16 b[4]; } u;
#pragma unroll
            for (int j = 0; j < 4; ++j) u.b[j] = __float2bfloat16(silu_f(acc[ef][j]));
            *(short4v*)&sB1[ef * 16 + l15][nb] = u.s;
        }
        __syncthreads();   // B2

        // ---- layer 2: sB1 @ W2 -> silu = m -> sB2 (sX alias; sX reads done) ----
#pragma unroll
        for (int ef = 0; ef < 4; ++ef) {
            acc[ef][0] = b2v[0]; acc[ef][1] = b2v[1]; acc[ef][2] = b2v[2]; acc[ef][3] = b2v[3];
        }
#pragma unroll
        for (int s = 0; s < 4; ++s) {
            const short8 a = w2f[s];
#pragma unroll
            for (int ef = 0; ef < 4; ++ef) {
                const short8 b = *(const short8*)&sB1[ef * 16 + l15][s * 32 + kq];
                acc[ef] = __builtin_amdgcn_mfma_f32_16x16x32_bf16(a, b, acc[ef], 0, 0, 0);
            }
        }
#pragma unroll
        for (int ef = 0; ef < 4; ++ef) {
            union { short4v s; __hip_bfloat16 b[4]; } u;
#pragma unroll
            for (int j = 0; j < 4; ++j) u.b[j] = __float2bfloat16(silu_f(acc[ef][j]));
            *(short4v*)&sB2[ef * 16 + l15][nb] = u.s;
        }
        __syncthreads();   // B3

        // ---- layer 3: m @ c_w1 -> silu -> sB1 (MFMA only; atomics deferred) ----
#pragma unroll
        for (int ef = 0; ef < 4; ++ef) {
            acc[ef][0] = b3v[0]; acc[ef][1] = b3v[1]; acc[ef][2] = b3v[2]; acc[ef][3] = b3v[3];
        }
#pragma unroll
        for (int s = 0; s < 4; ++s) {
            const short8 a = w3f[s];
#pragma unroll
            for (int ef = 0; ef < 4; ++ef) {
                const short8 b = *(const short8*)&sB2[ef * 16 + l15][s * 32 + kq];
                acc[ef] = __builtin_amdgcn_mfma_f32_16x16x32_bf16(a, b, acc[ef], 0, 0, 0);
            }
        }
#pragma unroll
        for (int ef = 0; ef < 4; ++ef) {
            union { short4v s; __hip_bfloat16 b[4]; } u;
#pragma unroll
            for (int j = 0; j < 4; ++j) u.b[j] = __float2bfloat16(silu_f(acc[ef][j]));
            *(short4v*)&sB1[ef * 16 + l15][nb] = u.s;
        }
        __syncthreads();   // B4

        // ---- coord-out via MFMA (register cwtf): s_w = sB1 @ c_wout^T ----
        if (wv < 4) {
            f32x4 cacc = {0.0f, 0.0f, 0.0f, 0.0f};
#pragma unroll
            for (int s = 0; s < 4; ++s) {
                const short8 b = *(const short8*)&sB1[wv * 16 + l15][s * 32 + kq];
                cacc = __builtin_amdgcn_mfma_f32_16x16x32_bf16(cwtf[s], b, cacc, 0, 0, 0);
            }
            if (lane < 16) {
#pragma unroll
                for (int j = 0; j < 4; ++j) s_w[wv * 16 + l15][j] = cacc[j];
            }
        }
        __syncthreads();   // B5

        // ---- final phase: nagg run-sum (reads sB2, intact) + cagg; one drain ----
        {
            const int q = tid >> 7, c = tid & 127;
            int e = q * 16;
            const int eend = min(e + 16, nE);
            if (e < eend) {
                int cur = s_segid[e];
                float sum = 0.0f;
                for (; e < eend; ++e) {
                    const int sg = s_segid[e];
                    if (sg != cur) {
                        atomicAdd(&nagg[(size_t)s_segrow[cur] * 128 + c], sum);
                        sum = 0.0f; cur = sg;
                    }
                    sum += bf2f(sB2[e][c]);
                }
                atomicAdd(&nagg[(size_t)s_segrow[cur] * 128 + c], sum);
            }
        }
        {
            const int nseg = s_nseg;
            const int items = nseg * 48;
            for (int i = tid; i < items; i += 512) {
                const int s = i / 48, r = i - s * 48;
                const int q = r / 12, dd = r - q * 12;
                const int b  = max(s_segstart[s], q * 16);
                const int en = min(s_segstart[s + 1], q * 16 + 16);
                if (b < en) {
                    float sum = 0.0f;
                    for (int e = b; e < en; ++e)
                        sum += s_diff[e][dd] * s_w[e][dd / 3];
                    atomicAdd(&cagg[(size_t)s_segrow[s] * 12 + dd], sum);
                }
            }
        }
        __syncthreads();   // B6
    }
}

// ---------------------------------------------------------------------------
// Node MLP on MFMA: 64-node tiles, 8 waves x 16 neurons, register weights.
// ---------------------------------------------------------------------------
constexpr int NXS = 264;  // 256 + 8 pad

__global__ __launch_bounds__(512, 2) void k_node_mfma(
    const float* __restrict__ h, const float* __restrict__ nagg,
    const __hip_bfloat16* __restrict__ nw1t, const __hip_bfloat16* __restrict__ nw2t,
    const float* __restrict__ n_b1, const float* __restrict__ n_b2,
    const float* __restrict__ coord, const float* __restrict__ cagg,
    const int* __restrict__ row_ptr,
    float* __restrict__ out_h, float* __restrict__ out_coord, int N)
{
    __shared__ __hip_bfloat16 sX[64][NXS];
    __shared__ __hip_bfloat16 sB[64][BS];

    const int tid = threadIdx.x;
    const int wv = tid >> 6;
    const int lane = tid & 63, l15 = lane & 15;
    const int kq = (lane >> 4) * 8;
    const int jr = (lane >> 4) * 4;
    const int nb = wv * 16 + jr;

    short8 w1f[8], w2f[4];
    float b1v[4], b2v[4];
    {
        const int nrow = wv * 16 + l15;
#pragma unroll
        for (int s = 0; s < 8; ++s) w1f[s] = *(const short8*)&nw1t[nrow * 256 + s * 32 + kq];
#pragma unroll
        for (int s = 0; s < 4; ++s) w2f[s] = *(const short8*)&nw2t[nrow * 128 + s * 32 + kq];
#pragma unroll
        for (int j = 0; j < 4; ++j) { b1v[j] = n_b1[nb + j]; b2v[j] = n_b2[nb + j]; }
    }

    const int n0 = blockIdx.x * 64;
    const int nN = min(64, N - n0);

    // coord epilogue (independent of the MLP)
    for (int i = tid; i < nN * 12; i += 512) {
        const int e = i / 12, dd = i - e * 12;
        const int n = n0 + e;
        const float cntv = (float)(row_ptr[n + 1] - row_ptr[n]);
        out_coord[n * 12 + dd] = coord[n * 12 + dd] + cagg[n * 12 + dd] / fmaxf(cntv, 1.0f);
    }

    // stage X = [h | nagg] as bf16
    {
        const int e = tid >> 3, p = tid & 7;
        const int n = n0 + e;
        union { short8 s; __hip_bfloat16 b[8]; } u;
        if (e < nN) {
            const float* src = (p < 4) ? &h[(size_t)n * 128 + p * 32]
                                       : &nagg[(size_t)n * 128 + (p - 4) * 32];
#pragma unroll
            for (int i = 0; i < 4; ++i) {
                const float4 v0 = *(const float4*)(src + i * 8);
                const float4 v1 = *(const float4*)(src + i * 8 + 4);
                u.b[0] = __float2bfloat16(v0.x); u.b[1] = __float2bfloat16(v0.y);
                u.b[2] = __float2bfloat16(v0.z); u.b[3] = __float2bfloat16(v0.w);
                u.b[4] = __float2bfloat16(v1.x); u.b[5] = __float2bfloat16(v1.y);
                u.b[6] = __float2bfloat16(v1.z); u.b[7] = __float2bfloat16(v1.w);
                *(short8*)&sX[e][p * 32 + i * 8] = u.s;
            }
        } else {
#pragma unroll
            for (int j = 0; j < 8; ++j) u.b[j] = __float2bfloat16(0.0f);
#pragma unroll
            for (int i = 0; i < 4; ++i) *(short8*)&sX[e][p * 32 + i * 8] = u.s;
        }
    }
    __syncthreads();

    f32x4 acc[4];
#pragma unroll
    for (int ef = 0; ef < 4; ++ef) {
        acc[ef][0] = b1v[0]; acc[ef][1] = b1v[1]; acc[ef][2] = b1v[2]; acc[ef][3] = b1v[3];
    }
#pragma unroll
    for (int s = 0; s < 8; ++s) {
        const short8 a = w1f[s];
#pragma unroll
        for (int ef = 0; ef < 4; ++ef) {
            const short8 b = *(const short8*)&sX[ef * 16 + l15][s * 32 + kq];
            acc[ef] = __builtin_amdgcn_mfma_f32_16x16x32_bf16(a, b, acc[ef], 0, 0, 0);
        }
    }
#pragma unroll
    for (int ef = 0; ef < 4; ++ef) {
        union { short4v s; __hip_bfloat16 b[4]; } u;
#pragma unroll
        for (int j = 0; j < 4; ++j) u.b[j] = __float2bfloat16(silu_f(acc[ef][j]));
        *(short4v*)&sB[ef * 16 + l15][nb] = u.s;
    }
    __syncthreads();

#pragma unroll
    for (int ef = 0; ef < 4; ++ef) {
        acc[ef][0] = b2v[0]; acc[ef][1] = b2v[1]; acc[ef][2] = b2v[2]; acc[ef][3] = b2v[3];
    }
#pragma unroll
    for (int s = 0; s < 4; ++s) {
        const short8 a = w2f[s];
#pragma unroll
        for (int ef = 0; ef < 4; ++ef) {
            const short8 b = *(const short8*)&sB[ef * 16 + l15][s * 32 + kq];
            acc[ef] = __builtin_amdgcn_mfma_f32_16x16x32_bf16(a, b, acc[ef], 0, 0, 0);
        }
    }
#pragma unroll
    for (int ef = 0; ef < 4; ++ef) {
        const int e = ef * 16 + l15;
        if (e < nN) {
            const size_t o = (size_t)(n0 + e) * 128 + nb;
            const float4 hv = *(const float4*)&h[o];
            float4 r;
            r.x = hv.x + acc[ef][0]; r.y = hv.y + acc[ef][1];
            r.z = hv.z + acc[ef][2]; r.w = hv.w + acc[ef][3];
            *(float4*)&out_h[o] = r;
        }
    }
}

// ---------------------------------------------------------------------------
extern "C" void kernel_launch(void* const* d_in, const int* in_sizes, int n_in,
                              void* d_out, int out_size, void* d_ws, size_t ws_size,
                              hipStream_t stream)
{
    const float* h      = (const float*)d_in[0];
    const float* coord  = (const float*)d_in[1];
    const int*   row    = (const int*)d_in[2];
    const int*   col    = (const int*)d_in[3];
    const float* e_w1   = (const float*)d_in[4];
    const float* e_b1   = (const float*)d_in[5];
    const float* e_w2   = (const float*)d_in[6];
    const float* e_b2   = (const float*)d_in[7];
    const float* c_w1   = (const float*)d_in[8];
    const float* c_b1   = (const float*)d_in[9];
    const float* c_wout = (const float*)d_in[10];
    const float* n_w1   = (const float*)d_in[11];
    const float* n_b1   = (const float*)d_in[12];
    const float* n_w2   = (const float*)d_in[13];
    const float* n_b2   = (const float*)d_in[14];

    const int E = in_sizes[2];
    const int N = in_sizes[0] / 128;

    // workspace layout (zeroed region first) — ~7.25 MB
    float* ws       = (float*)d_ws;
    float* norm_acc = ws;                               // 32
    int*   deg      = (int*)(ws + 32);                  // N
    int*   cur      = deg + N;                          // N
    float* nagg     = (float*)(cur + N);                // N*128
    float* cagg     = nagg + (size_t)N * 128;           // N*12
    // non-zeroed:
    int*   row_ptr  = (int*)(cagg + (size_t)N * 12);    // N+1 (rounded)
    int*   csr      = row_ptr + ((N + 4) & ~3);         // E
    float* inv_norm = (float*)(csr + E);                // 32
    __hip_bfloat16* w1t  = (__hip_bfloat16*)(inv_norm + 32);  // 36864
    __hip_bfloat16* w2t  = w1t + 36864;                       // 16384
    __hip_bfloat16* c1t  = w2t + 16384;                       // 16384
    __hip_bfloat16* cwt  = c1t + 16384;                       // 2176
    __hip_bfloat16* nw1t = cwt + 2176;                        // 32768
    __hip_bfloat16* nw2t = nw1t + 32768;                      // 16384

    // bf16 h table in d_out (dead until k_node_mfma overwrites it)
    __hip_bfloat16* hb = (__hip_bfloat16*)d_out;              // N*128 bf16

    const size_t zero_bytes = (size_t)(32 + 2 * N + N * 128 + N * 12) * sizeof(float);
    hipMemsetAsync(d_ws, 0, zero_bytes, stream);

    const int prepH_B = (N * 64 + 255) / 256;
    k_prep_all<<<PREP_B + prepH_B + HIST_B, 256, 0, stream>>>(
        e_w1, e_w2, c_w1, c_wout, n_w1, n_w2, h, coord, row, col,
        w1t, w2t, c1t, cwt, nw1t, nw2t, hb, N * 128,
        deg, norm_acc, E, prepH_B);
    k_scanfin<<<1, 1024, 0, stream>>>(deg, row_ptr, norm_acc, inv_norm, N);
    k_scatter<<<(E + 255) / 256, 256, 0, stream>>>(row, row_ptr, cur, csr, E);

    const int nTiles = (E + TE - 1) / TE;
    k_edge_mfma<<<512, 512, 0, stream>>>(
        hb, coord, row, col, csr, w1t, w2t, c1t, cwt,
        e_b1, e_b2, c_b1, inv_norm, nagg, cagg, E, nTiles);

    float* out_h     = (float*)d_out;
    float* out_coord = out_h + (size_t)N * 128;
    k_node_mfma<<<(N + 63) / 64, 512, 0, stream>>>(
        h, nagg, nw1t, nw2t, n_b1, n_b2, coord, cagg, row_ptr, out_h, out_coord, N);
}

// Round 16
// 247.991 us; speedup vs baseline: 1.2671x; 1.1529x over previous
//
#include <hip/hip_runtime.h>
#include <hip/hip_bf16.h>

// EGNN layer (MC_E_GCL). FINAL: round-12 champion verbatim (248.1us, 4.9x over
// f32 baseline). Edge pipeline: CSR-sorted 64-edge tiles, bf16 MFMA with
// weight fragments loaded once per kernel (unified VGPR/AGPR file), segmented
// scatter (one atomic per tile-segment), MFMA node MLP, fused setup kernels.
// Refuted levers (kept for the record): register prefetch/T14 (allocator pins
// 64 arch-VGPRs, spills), occupancy via smaller tiles (TE=48/32 regressed),
// phase fusion (induces spill), forced waves_per_eu (no-op or regression).

typedef __attribute__((ext_vector_type(8))) short short8;
typedef __attribute__((ext_vector_type(4))) short short4v;
typedef __attribute__((ext_vector_type(4))) float f32x4;

__device__ __forceinline__ float silu_f(float x) {
    return x / (1.0f + __expf(-x));
}
__device__ __forceinline__ float bf2f(__hip_bfloat16 b) { return __bfloat162float(b); }

// ---------------------------------------------------------------------------
// Setup A (fused): weight transposes + bf16 h table + {deg histogram, norms}.
// ---------------------------------------------------------------------------
constexpr int PREP_ITEMS = 120960;
constexpr int PREP_B     = (PREP_ITEMS + 255) / 256;   // 473
constexpr int HIST_B     = 640;

__global__ void k_prep_all(const float* __restrict__ e_w1, const float* __restrict__ e_w2,
                           const float* __restrict__ c_w1, const float* __restrict__ c_wout,
                           const float* __restrict__ n_w1, const float* __restrict__ n_w2,
                           const float* __restrict__ h,
                           const float* __restrict__ coord,
                           const int* __restrict__ row, const int* __restrict__ col,
                           __hip_bfloat16* __restrict__ w1t, __hip_bfloat16* __restrict__ w2t,
                           __hip_bfloat16* __restrict__ c1t, __hip_bfloat16* __restrict__ cwt,
                           __hip_bfloat16* __restrict__ nw1t, __hip_bfloat16* __restrict__ nw2t,
                           __hip_bfloat16* __restrict__ hb, int hTotal,
                           int* __restrict__ deg, float* __restrict__ norm_acc, int E,
                           int prepH_B)
{
    __shared__ float s_red[32];

    if (blockIdx.x < PREP_B) {
        const int i = blockIdx.x * 256 + threadIdx.x;
        if (i < 36864) {                       // e_w1^T [128][288]
            const int n = i / 288, k = i - n * 288;
            w1t[i] = __float2bfloat16(e_w1[k * 128 + n]);
        } else if (i < 53248) {                // e_w2^T [128][128]
            const int j = i - 36864, n = j >> 7, k = j & 127;
            w2t[j] = __float2bfloat16(e_w2[k * 128 + n]);
        } else if (i < 69632) {                // c_w1^T [128][128]
            const int j = i - 53248, n = j >> 7, k = j & 127;
            c1t[j] = __float2bfloat16(c_w1[k * 128 + n]);
        } else if (i < 71808) {                // c_wout^T padded [16][136]
            const int j = i - 69632, n = j / 136, k = j - n * 136;
            cwt[j] = (n < 4 && k < 128) ? __float2bfloat16(c_wout[k * 4 + n])
                                        : __float2bfloat16(0.0f);
        } else if (i < 104576) {               // n_w1^T [128][256]
            const int j = i - 71808, n = j >> 8, k = j & 255;
            nw1t[j] = __float2bfloat16(n_w1[k * 128 + n]);
        } else if (i < 120960) {               // n_w2^T [128][128]
            const int j = i - 104576, n = j >> 7, k = j & 127;
            nw2t[j] = __float2bfloat16(n_w2[k * 128 + n]);
        }
        return;
    }
    if (blockIdx.x < PREP_B + prepH_B) {       // h -> bf16 table
        const int i = (blockIdx.x - PREP_B) * 256 + threadIdx.x;
        if (i * 2 < hTotal) {
            const float2 v = *(const float2*)&h[i * 2];
            union { ushort2 u; __hip_bfloat16 b[2]; } p;
            p.b[0] = __float2bfloat16(v.x);
            p.b[1] = __float2bfloat16(v.y);
            *(ushort2*)&hb[i * 2] = p.u;
        }
        return;
    }

    // ---- histogram + norm accumulators (grid-stride over edges) ----
    const int hb0 = PREP_B + prepH_B;
    float p[32];
#pragma unroll
    for (int i = 0; i < 32; ++i) p[i] = 0.0f;

    for (int e = (blockIdx.x - hb0) * blockDim.x + threadIdx.x; e < E;
         e += HIST_B * blockDim.x) {
        const int r = row[e], c = col[e];
        atomicAdd(&deg[r], 1);
        float ci[12], cj[12], d[12];
#pragma unroll
        for (int i = 0; i < 12; ++i) {
            ci[i] = coord[r * 12 + i];
            cj[i] = coord[c * 12 + i];
            d[i] = ci[i] - cj[i];
        }
#pragma unroll
        for (int a = 0; a < 4; ++a) {
#pragma unroll
            for (int b = 0; b < 4; ++b) {
                const float rad = d[a*3+0]*d[b*3+0] + d[a*3+1]*d[b*3+1] + d[a*3+2]*d[b*3+2];
                p[a*8 + b] += rad * rad;
                const float dx = ci[a*3+0] - cj[b*3+0];
                const float dy = ci[a*3+1] - cj[b*3+1];
                const float dz = ci[a*3+2] - cj[b*3+2];
                p[a*8 + 4 + b] += dx*dx + dy*dy + dz*dz;   // dist^2 (no sqrt)
            }
        }
    }

    if (threadIdx.x < 32) s_red[threadIdx.x] = 0.0f;
    __syncthreads();
#pragma unroll
    for (int i = 0; i < 32; ++i) {
        float v = p[i];
        for (int off = 32; off >= 1; off >>= 1) v += __shfl_down(v, off, 64);
        if ((threadIdx.x & 63) == 0) atomicAdd(&s_red[i], v);
    }
    __syncthreads();
    if (threadIdx.x < 32) atomicAdd(&norm_acc[threadIdx.x], s_red[threadIdx.x]);
}

// ---------------------------------------------------------------------------
// Setup C: 1024-thread scan of deg -> row_ptr ; + inv-norm finalize.
// ---------------------------------------------------------------------------
__global__ void k_scanfin(const int* __restrict__ deg, int* __restrict__ row_ptr,
                          const float* __restrict__ norm_acc, float* __restrict__ inv_norm,
                          int N)
{
    const int t = threadIdx.x;
    if (t < 32) inv_norm[t] = 1.0f / fmaxf(sqrtf(norm_acc[t]), 1e-12f);

    __shared__ int s[1024];
    const int chunk = (N + 1023) / 1024;
    const int lo = t * chunk, hi = min(lo + chunk, N);
    int sum = 0;
    for (int i = lo; i < hi; ++i) sum += deg[i];
    s[t] = sum;
    __syncthreads();
    for (int off = 1; off < 1024; off <<= 1) {
        int v = (t >= off) ? s[t - off] : 0;
        __syncthreads();
        s[t] += v;
        __syncthreads();
    }
    int running = s[t] - sum;
    for (int i = lo; i < hi; ++i) { row_ptr[i] = running; running += deg[i]; }
    if (hi == N) row_ptr[N] = running + (s[1023] - s[t]);
}

__global__ void k_scatter(const int* __restrict__ row, const int* __restrict__ row_ptr,
                          int* __restrict__ cur, int* __restrict__ csr, int E)
{
    const int e = blockIdx.x * 256 + threadIdx.x;
    if (e < E) {
        const int r = row[e];
        const int idx = row_ptr[r] + atomicAdd(&cur[r], 1);
        csr[idx] = e;
    }
}

// ---------------------------------------------------------------------------
// Edge pipeline (7 barriers). 8 waves x 16 neurons over 64-edge sorted tiles.
// ---------------------------------------------------------------------------
constexpr int XS = 296;   // 256 h_row|h_col + 32 rad + 8 pad
constexpr int BS = 136;   // 128 + 8 pad

__global__ __launch_bounds__(512)
__attribute__((amdgpu_waves_per_eu(4, 4)))
void k_edge_mfma(
    const __hip_bfloat16* __restrict__ hb, const float* __restrict__ coord,
    const int* __restrict__ row, const int* __restrict__ col,
    const int* __restrict__ csr,
    const __hip_bfloat16* __restrict__ w1t, const __hip_bfloat16* __restrict__ w2t,
    const __hip_bfloat16* __restrict__ c1t, const __hip_bfloat16* __restrict__ cwt,
    const float* __restrict__ e_b1, const float* __restrict__ e_b2,
    const float* __restrict__ c_b1, const float* __restrict__ inv_norm,
    float* __restrict__ nagg, float* __restrict__ cagg,
    int E, int nTiles)
{
    __shared__ __hip_bfloat16 sX[64][XS];
    __shared__ __hip_bfloat16 sB1[64][BS];
    __shared__ float s_diff[64][12];
    __shared__ float s_w[64][4];
    __shared__ float s_inv[32];
    __shared__ int   s_rowv[64];
    __shared__ int   s_segid[64];
    __shared__ int   s_segstart[65];
    __shared__ int   s_segrow[64];
    __shared__ int   s_nseg;
    __hip_bfloat16 (*sB2)[BS] = (__hip_bfloat16 (*)[BS])&sX[0][0];   // alias sX
    float (*s_ci)[12] = (float (*)[12])&sB1[0][0];                    // alias sB1
    float (*s_cj)[12] = s_ci + 64;

    const int tid = threadIdx.x;
    const int wv = tid >> 6;
    const int lane = tid & 63, l15 = lane & 15;
    const int kq = (lane >> 4) * 8;
    const int jr = (lane >> 4) * 4;
    const int nb = wv * 16 + jr;

    if (tid < 32) s_inv[tid] = inv_norm[tid];

    // register/AGPR-resident weights + biases + c_wout fragments
    short8 w1f[9], w2f[4], w3f[4], cwtf[4];
    float b1v[4], b2v[4], b3v[4];
    {
        const int nrow = wv * 16 + l15;
#pragma unroll
        for (int s = 0; s < 9; ++s) w1f[s] = *(const short8*)&w1t[nrow * 288 + s * 32 + kq];
#pragma unroll
        for (int s = 0; s < 4; ++s) w2f[s] = *(const short8*)&w2t[nrow * 128 + s * 32 + kq];
#pragma unroll
        for (int s = 0; s < 4; ++s) w3f[s] = *(const short8*)&c1t[nrow * 128 + s * 32 + kq];
#pragma unroll
        for (int s = 0; s < 4; ++s) cwtf[s] = *(const short8*)&cwt[l15 * 136 + s * 32 + kq];
#pragma unroll
        for (int j = 0; j < 4; ++j) {
            b1v[j] = e_b1[nb + j]; b2v[j] = e_b2[nb + j]; b3v[j] = c_b1[nb + j];
        }
    }
    __syncthreads();

    for (int tile = blockIdx.x; tile < nTiles; tile += gridDim.x) {
        const int e0 = tile * 64;
        const int nE = min(64, E - e0);

        // ---- phase A: stage h[row], h[col] (16 bf16 = two short8 per slot) ----
        {
            const int e = tid >> 3, p = tid & 7;
            if (e < nE) {
                const int eid = csr[e0 + e];
                const int r = row[eid], c = col[eid];
                const __hip_bfloat16* hr = &hb[(size_t)r * 128 + p * 16];
                const __hip_bfloat16* hc = &hb[(size_t)c * 128 + p * 16];
                *(short8*)&sX[e][p * 16]           = *(const short8*)(hr);
                *(short8*)&sX[e][p * 16 + 8]       = *(const short8*)(hr + 8);
                *(short8*)&sX[e][128 + p * 16]     = *(const short8*)(hc);
                *(short8*)&sX[e][128 + p * 16 + 8] = *(const short8*)(hc + 8);
                if (p == 0) {
                    s_rowv[e] = r;
                    *(float4*)&s_ci[e][0] = *(const float4*)&coord[r * 12];
                    *(float4*)&s_ci[e][4] = *(const float4*)&coord[r * 12 + 4];
                    *(float4*)&s_ci[e][8] = *(const float4*)&coord[r * 12 + 8];
                } else if (p == 1) {
                    *(float4*)&s_cj[e][0] = *(const float4*)&coord[c * 12];
                    *(float4*)&s_cj[e][4] = *(const float4*)&coord[c * 12 + 4];
                    *(float4*)&s_cj[e][8] = *(const float4*)&coord[c * 12 + 8];
                }
            }
        }
        __syncthreads();   // B1

        // ---- phase B: rad features + segment build (with per-edge segid) ----
        {
            const int e = tid >> 3, pp = (tid & 7) * 2;
            if (e < nE) {
#pragma unroll
                for (int t2 = 0; t2 < 2; ++t2) {
                    const int pr = pp + t2, a = pr >> 2, b = pr & 3;
                    const float cax = s_ci[e][a*3], cay = s_ci[e][a*3+1], caz = s_ci[e][a*3+2];
                    const float jax = s_cj[e][a*3], jay = s_cj[e][a*3+1], jaz = s_cj[e][a*3+2];
                    const float cbx = s_ci[e][b*3], cby = s_ci[e][b*3+1], cbz = s_ci[e][b*3+2];
                    const float jbx = s_cj[e][b*3], jby = s_cj[e][b*3+1], jbz = s_cj[e][b*3+2];
                    const float dax = cax - jax, day = cay - jay, daz = caz - jaz;
                    const float dbx = cbx - jbx, dby = cby - jby, dbz = cbz - jbz;
                    const float rad = dax*dbx + day*dby + daz*dbz;
                    const float dx = cax - jbx, dy = cay - jby, dz = caz - jbz;
                    const float ds = sqrtf(dx*dx + dy*dy + dz*dz);
                    sX[e][256 + a*8 + b]     = __float2bfloat16(rad * s_inv[a*8 + b]);
                    sX[e][256 + a*8 + 4 + b] = __float2bfloat16(ds  * s_inv[a*8 + 4 + b]);
                    if (a == b) {
                        s_diff[e][a*3] = dax; s_diff[e][a*3+1] = day; s_diff[e][a*3+2] = daz;
                    }
                }
            }
        }
        if (tid < 64) {
            const int i = tid;
            const bool valid = i < nE;
            const int r = valid ? s_rowv[i] : -1;
            const bool flag = valid && (i == 0 || r != s_rowv[i - 1]);
            const unsigned long long mask = __ballot(flag);
            if (flag) {
                const int s = (i == 0) ? 0 : __popcll(mask & ((1ull << i) - 1));
                s_segstart[s] = i;
                s_segrow[s] = r;
            }
            // inclusive prefix popcount - 1 = segment id of edge i
            const unsigned long long upto =
                (i == 63) ? ~0ull : ((1ull << (i + 1)) - 1);
            if (valid) s_segid[i] = __popcll(mask & upto) - 1;
            if (i == 0) {
                const int nseg = __popcll(mask);
                s_nseg = nseg;
                s_segstart[nseg] = nE;
            }
        }
        __syncthreads();   // B2

        f32x4 acc[4];

        // ---- layer 1: eh @ W1 -> silu -> sB1 ----
#pragma unroll
        for (int ef = 0; ef < 4; ++ef) {
            acc[ef][0] = b1v[0]; acc[ef][1] = b1v[1]; acc[ef][2] = b1v[2]; acc[ef][3] = b1v[3];
        }
#pragma unroll
        for (int s = 0; s < 9; ++s) {
            const short8 a = w1f[s];
#pragma unroll
            for (int ef = 0; ef < 4; ++ef) {
                const short8 b = *(const short8*)&sX[ef * 16 + l15][s * 32 + kq];
                acc[ef] = __builtin_amdgcn_mfma_f32_16x16x32_bf16(a, b, acc[ef], 0, 0, 0);
            }
        }
#pragma unroll
        for (int ef = 0; ef < 4; ++ef) {
            union { short4v s; __hip_bfloat16 b[4]; } u;
#pragma unroll
            for (int j = 0; j < 4; ++j) u.b[j] = __float2bfloat16(silu_f(acc[ef][j]));
            *(short4v*)&sB1[ef * 16 + l15][nb] = u.s;
        }
        __syncthreads();   // B3

        // ---- layer 2: sB1 @ W2 -> silu = m -> sB2 (sX alias; sX reads done) ----
#pragma unroll
        for (int ef = 0; ef < 4; ++ef) {
            acc[ef][0] = b2v[0]; acc[ef][1] = b2v[1]; acc[ef][2] = b2v[2]; acc[ef][3] = b2v[3];
        }
#pragma unroll
        for (int s = 0; s < 4; ++s) {
            const short8 a = w2f[s];
#pragma unroll
            for (int ef = 0; ef < 4; ++ef) {
                const short8 b = *(const short8*)&sB1[ef * 16 + l15][s * 32 + kq];
                acc[ef] = __builtin_amdgcn_mfma_f32_16x16x32_bf16(a, b, acc[ef], 0, 0, 0);
            }
        }
#pragma unroll
        for (int ef = 0; ef < 4; ++ef) {
            union { short4v s; __hip_bfloat16 b[4]; } u;
#pragma unroll
            for (int j = 0; j < 4; ++j) u.b[j] = __float2bfloat16(silu_f(acc[ef][j]));
            *(short4v*)&sB2[ef * 16 + l15][nb] = u.s;
        }
        __syncthreads();   // B4

        // ---- layer 3: m @ c_w1 -> silu -> sB1 ; parallel nagg run-sum ----
#pragma unroll
        for (int ef = 0; ef < 4; ++ef) {
            acc[ef][0] = b3v[0]; acc[ef][1] = b3v[1]; acc[ef][2] = b3v[2]; acc[ef][3] = b3v[3];
        }
#pragma unroll
        for (int s = 0; s < 4; ++s) {
            const short8 a = w3f[s];
#pragma unroll
            for (int ef = 0; ef < 4; ++ef) {
                const short8 b = *(const short8*)&sB2[ef * 16 + l15][s * 32 + kq];
                acc[ef] = __builtin_amdgcn_mfma_f32_16x16x32_bf16(a, b, acc[ef], 0, 0, 0);
            }
        }
        // nagg: all 512 threads; 16-edge run per (quarter, channel); flush
        // one atomic per segment-run.
        {
            const int q = tid >> 7, c = tid & 127;
            int e = q * 16;
            const int eend = min(e + 16, nE);
            if (e < eend) {
                int cur = s_segid[e];
                float sum = 0.0f;
                for (; e < eend; ++e) {
                    const int sg = s_segid[e];
                    if (sg != cur) {
                        atomicAdd(&nagg[(size_t)s_segrow[cur] * 128 + c], sum);
                        sum = 0.0f; cur = sg;
                    }
                    sum += bf2f(sB2[e][c]);
                }
                atomicAdd(&nagg[(size_t)s_segrow[cur] * 128 + c], sum);
            }
        }
#pragma unroll
        for (int ef = 0; ef < 4; ++ef) {
            union { short4v s; __hip_bfloat16 b[4]; } u;
#pragma unroll
            for (int j = 0; j < 4; ++j) u.b[j] = __float2bfloat16(silu_f(acc[ef][j]));
            *(short4v*)&sB1[ef * 16 + l15][nb] = u.s;
        }
        __syncthreads();   // B5

        // ---- coord-out via MFMA (register cwtf): s_w = sB1 @ c_wout^T ----
        if (wv < 4) {
            f32x4 cacc = {0.0f, 0.0f, 0.0f, 0.0f};
#pragma unroll
            for (int s = 0; s < 4; ++s) {
                const short8 b = *(const short8*)&sB1[wv * 16 + l15][s * 32 + kq];
                cacc = __builtin_amdgcn_mfma_f32_16x16x32_bf16(cwtf[s], b, cacc, 0, 0, 0);
            }
            if (lane < 16) {
#pragma unroll
                for (int j = 0; j < 4; ++j) s_w[wv * 16 + l15][j] = cacc[j];
            }
        }
        __syncthreads();   // B6

        // ---- cagg: parallel segmented reduction over (seg, quarter, dd) ----
        {
            const int nseg = s_nseg;
            const int items = nseg * 48;
            for (int i = tid; i < items; i += 512) {
                const int s = i / 48, r = i - s * 48;
                const int q = r / 12, dd = r - q * 12;
                const int b  = max(s_segstart[s], q * 16);
                const int en = min(s_segstart[s + 1], q * 16 + 16);
                if (b < en) {
                    float sum = 0.0f;
                    for (int e = b; e < en; ++e)
                        sum += s_diff[e][dd] * s_w[e][dd / 3];
                    atomicAdd(&cagg[(size_t)s_segrow[s] * 12 + dd], sum);
                }
            }
        }
        __syncthreads();   // B7
    }
}

// ---------------------------------------------------------------------------
// Node MLP on MFMA: 64-node tiles, 8 waves x 16 neurons, register weights.
// ---------------------------------------------------------------------------
constexpr int NXS = 264;  // 256 + 8 pad

__global__ __launch_bounds__(512, 2) void k_node_mfma(
    const float* __restrict__ h, const float* __restrict__ nagg,
    const __hip_bfloat16* __restrict__ nw1t, const __hip_bfloat16* __restrict__ nw2t,
    const float* __restrict__ n_b1, const float* __restrict__ n_b2,
    const float* __restrict__ coord, const float* __restrict__ cagg,
    const int* __restrict__ row_ptr,
    float* __restrict__ out_h, float* __restrict__ out_coord, int N)
{
    __shared__ __hip_bfloat16 sX[64][NXS];
    __shared__ __hip_bfloat16 sB[64][BS];

    const int tid = threadIdx.x;
    const int wv = tid >> 6;
    const int lane = tid & 63, l15 = lane & 15;
    const int kq = (lane >> 4) * 8;
    const int jr = (lane >> 4) * 4;
    const int nb = wv * 16 + jr;

    short8 w1f[8], w2f[4];
    float b1v[4], b2v[4];
    {
        const int nrow = wv * 16 + l15;
#pragma unroll
        for (int s = 0; s < 8; ++s) w1f[s] = *(const short8*)&nw1t[nrow * 256 + s * 32 + kq];
#pragma unroll
        for (int s = 0; s < 4; ++s) w2f[s] = *(const short8*)&nw2t[nrow * 128 + s * 32 + kq];
#pragma unroll
        for (int j = 0; j < 4; ++j) { b1v[j] = n_b1[nb + j]; b2v[j] = n_b2[nb + j]; }
    }

    const int n0 = blockIdx.x * 64;
    const int nN = min(64, N - n0);

    // coord epilogue (independent of the MLP)
    for (int i = tid; i < nN * 12; i += 512) {
        const int e = i / 12, dd = i - e * 12;
        const int n = n0 + e;
        const float cntv = (float)(row_ptr[n + 1] - row_ptr[n]);
        out_coord[n * 12 + dd] = coord[n * 12 + dd] + cagg[n * 12 + dd] / fmaxf(cntv, 1.0f);
    }

    // stage X = [h | nagg] as bf16
    {
        const int e = tid >> 3, p = tid & 7;
        const int n = n0 + e;
        union { short8 s; __hip_bfloat16 b[8]; } u;
        if (e < nN) {
            const float* src = (p < 4) ? &h[(size_t)n * 128 + p * 32]
                                       : &nagg[(size_t)n * 128 + (p - 4) * 32];
#pragma unroll
            for (int i = 0; i < 4; ++i) {
                const float4 v0 = *(const float4*)(src + i * 8);
                const float4 v1 = *(const float4*)(src + i * 8 + 4);
                u.b[0] = __float2bfloat16(v0.x); u.b[1] = __float2bfloat16(v0.y);
                u.b[2] = __float2bfloat16(v0.z); u.b[3] = __float2bfloat16(v0.w);
                u.b[4] = __float2bfloat16(v1.x); u.b[5] = __float2bfloat16(v1.y);
                u.b[6] = __float2bfloat16(v1.z); u.b[7] = __float2bfloat16(v1.w);
                *(short8*)&sX[e][p * 32 + i * 8] = u.s;
            }
        } else {
#pragma unroll
            for (int j = 0; j < 8; ++j) u.b[j] = __float2bfloat16(0.0f);
#pragma unroll
            for (int i = 0; i < 4; ++i) *(short8*)&sX[e][p * 32 + i * 8] = u.s;
        }
    }
    __syncthreads();

    f32x4 acc[4];
#pragma unroll
    for (int ef = 0; ef < 4; ++ef) {
        acc[ef][0] = b1v[0]; acc[ef][1] = b1v[1]; acc[ef][2] = b1v[2]; acc[ef][3] = b1v[3];
    }
#pragma unroll
    for (int s = 0; s < 8; ++s) {
        const short8 a = w1f[s];
#pragma unroll
        for (int ef = 0; ef < 4; ++ef) {
            const short8 b = *(const short8*)&sX[ef * 16 + l15][s * 32 + kq];
            acc[ef] = __builtin_amdgcn_mfma_f32_16x16x32_bf16(a, b, acc[ef], 0, 0, 0);
        }
    }
#pragma unroll
    for (int ef = 0; ef < 4; ++ef) {
        union { short4v s; __hip_bfloat16 b[4]; } u;
#pragma unroll
        for (int j = 0; j < 4; ++j) u.b[j] = __float2bfloat16(silu_f(acc[ef][j]));
        *(short4v*)&sB[ef * 16 + l15][nb] = u.s;
    }
    __syncthreads();

#pragma unroll
    for (int ef = 0; ef < 4; ++ef) {
        acc[ef][0] = b2v[0]; acc[ef][1] = b2v[1]; acc[ef][2] = b2v[2]; acc[ef][3] = b2v[3];
    }
#pragma unroll
    for (int s = 0; s < 4; ++s) {
        const short8 a = w2f[s];
#pragma unroll
        for (int ef = 0; ef < 4; ++ef) {
            const short8 b = *(const short8*)&sB[ef * 16 + l15][s * 32 + kq];
            acc[ef] = __builtin_amdgcn_mfma_f32_16x16x32_bf16(a, b, acc[ef], 0, 0, 0);
        }
    }
#pragma unroll
    for (int ef = 0; ef < 4; ++ef) {
        const int e = ef * 16 + l15;
        if (e < nN) {
            const size_t o = (size_t)(n0 + e) * 128 + nb;
            const float4 hv = *(const float4*)&h[o];
            float4 r;
            r.x = hv.x + acc[ef][0]; r.y = hv.y + acc[ef][1];
            r.z = hv.z + acc[ef][2]; r.w = hv.w + acc[ef][3];
            *(float4*)&out_h[o] = r;
        }
    }
}

// ---------------------------------------------------------------------------
extern "C" void kernel_launch(void* const* d_in, const int* in_sizes, int n_in,
                              void* d_out, int out_size, void* d_ws, size_t ws_size,
                              hipStream_t stream)
{
    const float* h      = (const float*)d_in[0];
    const float* coord  = (const float*)d_in[1];
    const int*   row    = (const int*)d_in[2];
    const int*   col    = (const int*)d_in[3];
    const float* e_w1   = (const float*)d_in[4];
    const float* e_b1   = (const float*)d_in[5];
    const float* e_w2   = (const float*)d_in[6];
    const float* e_b2   = (const float*)d_in[7];
    const float* c_w1   = (const float*)d_in[8];
    const float* c_b1   = (const float*)d_in[9];
    const float* c_wout = (const float*)d_in[10];
    const float* n_w1   = (const float*)d_in[11];
    const float* n_b1   = (const float*)d_in[12];
    const float* n_w2   = (const float*)d_in[13];
    const float* n_b2   = (const float*)d_in[14];

    const int E = in_sizes[2];
    const int N = in_sizes[0] / 128;

    // workspace layout (zeroed region first) — ~7.25 MB
    float* ws       = (float*)d_ws;
    float* norm_acc = ws;                               // 32
    int*   deg      = (int*)(ws + 32);                  // N
    int*   cur      = deg + N;                          // N
    float* nagg     = (float*)(cur + N);                // N*128
    float* cagg     = nagg + (size_t)N * 128;           // N*12
    // non-zeroed:
    int*   row_ptr  = (int*)(cagg + (size_t)N * 12);    // N+1 (rounded)
    int*   csr      = row_ptr + ((N + 4) & ~3);         // E
    float* inv_norm = (float*)(csr + E);                // 32
    __hip_bfloat16* w1t  = (__hip_bfloat16*)(inv_norm + 32);  // 36864
    __hip_bfloat16* w2t  = w1t + 36864;                       // 16384
    __hip_bfloat16* c1t  = w2t + 16384;                       // 16384
    __hip_bfloat16* cwt  = c1t + 16384;                       // 2176
    __hip_bfloat16* nw1t = cwt + 2176;                        // 32768
    __hip_bfloat16* nw2t = nw1t + 32768;                      // 16384

    // bf16 h table in d_out (dead until k_node_mfma overwrites it)
    __hip_bfloat16* hb = (__hip_bfloat16*)d_out;              // N*128 bf16

    const size_t zero_bytes = (size_t)(32 + 2 * N + N * 128 + N * 12) * sizeof(float);
    hipMemsetAsync(d_ws, 0, zero_bytes, stream);

    const int prepH_B = (N * 64 + 255) / 256;
    k_prep_all<<<PREP_B + prepH_B + HIST_B, 256, 0, stream>>>(
        e_w1, e_w2, c_w1, c_wout, n_w1, n_w2, h, coord, row, col,
        w1t, w2t, c1t, cwt, nw1t, nw2t, hb, N * 128,
        deg, norm_acc, E, prepH_B);
    k_scanfin<<<1, 1024, 0, stream>>>(deg, row_ptr, norm_acc, inv_norm, N);
    k_scatter<<<(E + 255) / 256, 256, 0, stream>>>(row, row_ptr, cur, csr, E);

    const int nTiles = (E + 63) / 64;
    k_edge_mfma<<<512, 512, 0, stream>>>(
        hb, coord, row, col, csr, w1t, w2t, c1t, cwt,
        e_b1, e_b2, c_b1, inv_norm, nagg, cagg, E, nTiles);

    float* out_h     = (float*)d_out;
    float* out_coord = out_h + (size_t)N * 128;
    k_node_mfma<<<(N + 63) / 64, 512, 0, stream>>>(
        h, nagg, nw1t, nw2t, n_b1, n_b2, coord, cagg, row_ptr, out_h, out_coord, N);
}